// Round 12
// baseline (3532.079 us; speedup 1.0000x reference)
//
#include <hip/hip_runtime.h>
#include <hip/hip_fp16.h>

// ---------------------------------------------------------------------------
// BernNet forward: x@W1+b1 -> relu -> 2x BernConv(K=10) -> h@W2+b2
// Whole-row fp16 gather mirror (256B rows, pre-scaled u = dinv[v]*T[v], bare
// 4B col CSR). R12: gather restructured to 4 x (16-lane x 16B) -- each
// 16-lane group reads a full mirror row as float4-width loads, 4 edges in
// flight per unroll slot x 4-deep = 16 edges/iter, 4x in-flight bytes/wave
// vs R11 (tests latency- vs fabric-BW-bound). Mirror write fused into GEMM1.
// Trip counts wave-uniform (divergent __shfl undefined on CDNA); padding
// slots read dummy zero row n. f32 h-domain recurrence masters.
// ---------------------------------------------------------------------------

#define SCAN_BLOCK 256
#define SCAN_ITEMS 4
#define SCAN_CHUNK 1024

typedef float fx4 __attribute__((ext_vector_type(4)));

union f4h8 { fx4 f4; __half2 h2[4]; };

__global__ __launch_bounds__(256) void hist_kernel(const int* __restrict__ src,
                                                   const int* __restrict__ dst,
                                                   int* __restrict__ deg_src,
                                                   int* __restrict__ cnt_dst, int E) {
    int stride = gridDim.x * blockDim.x;
    for (int e = blockIdx.x * blockDim.x + threadIdx.x; e < E; e += stride) {
        atomicAdd(&deg_src[src[e]], 1);
        atomicAdd(&cnt_dst[dst[e]], 1);
    }
}

__global__ __launch_bounds__(256) void dinv_kernel(const int* __restrict__ deg,
                                                   float* __restrict__ dinv, int n) {
    int i = blockIdx.x * blockDim.x + threadIdx.x;
    if (i < n) {
        int d = deg[i];
        dinv[i] = d > 0 ? rsqrtf((float)d) : 0.f;
    }
}

__global__ __launch_bounds__(SCAN_BLOCK) void scan_chunk_sum(const int* __restrict__ cnt,
                                                             int* __restrict__ bsum, int n) {
    __shared__ int sdata[SCAN_BLOCK];
    int tid = threadIdx.x;
    int base = blockIdx.x * SCAN_CHUNK + tid * SCAN_ITEMS;
    int s = 0;
    for (int i = 0; i < SCAN_ITEMS; ++i) {
        int idx = base + i;
        if (idx < n) s += cnt[idx];
    }
    sdata[tid] = s;
    __syncthreads();
    for (int off = SCAN_BLOCK / 2; off > 0; off >>= 1) {
        if (tid < off) sdata[tid] += sdata[tid + off];
        __syncthreads();
    }
    if (tid == 0) bsum[blockIdx.x] = sdata[0];
}

__global__ void scan_bsum(int* __restrict__ bsum, int nb) {
    if (threadIdx.x == 0 && blockIdx.x == 0) {
        int run = 0;
        for (int i = 0; i < nb; ++i) {
            int v = bsum[i];
            bsum[i] = run;
            run += v;
        }
    }
}

__global__ __launch_bounds__(SCAN_BLOCK) void scan_write(const int* __restrict__ cnt,
                                                         const int* __restrict__ bsum,
                                                         int* __restrict__ rowptr,
                                                         int* __restrict__ cursor,
                                                         int n, int total) {
    __shared__ int sdata[SCAN_BLOCK];
    int tid = threadIdx.x;
    int base = blockIdx.x * SCAN_CHUNK + tid * SCAN_ITEMS;
    int vals[SCAN_ITEMS];
    int s = 0;
    for (int i = 0; i < SCAN_ITEMS; ++i) {
        int idx = base + i;
        vals[i] = (idx < n) ? cnt[idx] : 0;
        s += vals[i];
    }
    sdata[tid] = s;
    __syncthreads();
    for (int off = 1; off < SCAN_BLOCK; off <<= 1) {
        int add = (tid >= off) ? sdata[tid - off] : 0;
        __syncthreads();
        sdata[tid] += add;
        __syncthreads();
    }
    int run = bsum[blockIdx.x] + sdata[tid] - s;
    for (int i = 0; i < SCAN_ITEMS; ++i) {
        int idx = base + i;
        if (idx < n) {
            rowptr[idx] = run;
            cursor[idx] = run;
        }
        run += vals[i];
    }
    if (blockIdx.x == 0 && tid == 0) rowptr[n] = total;
}

// bare 4B record per edge: source index only (weights folded into mirror)
__global__ __launch_bounds__(256) void scatter_kernel(const int* __restrict__ src,
                                                      const int* __restrict__ dst,
                                                      int* __restrict__ cursor,
                                                      int* __restrict__ col, int E) {
    int stride = gridDim.x * blockDim.x;
    for (int e = blockIdx.x * blockDim.x + threadIdx.x; e < E; e += stride) {
        int d = dst[e];
        int p = atomicAdd(&cursor[d], 1);
        col[p] = src[e];
    }
}

// zero the dummy gather row (index n) of both mirrors (128 halves each)
__global__ void pad_kernel(__half* __restrict__ mA, __half* __restrict__ mB, int n) {
    int t = threadIdx.x;  // 256 threads
    if (t < 128) mA[(size_t)n * 128 + t] = __float2half(0.f);
    else mB[(size_t)n * 128 + (t - 128)] = __float2half(0.f);
}

// ------------- GEMM1: h = relu(x @ W1 + b1) + fused fp16 mirror ------------
#define G1_ROWS 16
__global__ __launch_bounds__(128) void gemm1_kernel(const float* __restrict__ X,
                                                    const float* __restrict__ W,
                                                    const float* __restrict__ b,
                                                    const float* __restrict__ dinv,
                                                    float* __restrict__ H,
                                                    __half* __restrict__ MH, int n) {
    __shared__ float xt[G1_ROWS][256];
    int j = threadIdx.x;
    int r0 = blockIdx.x * G1_ROWS;
    for (int i = threadIdx.x; i < G1_ROWS * 256; i += 128) {
        int r = i >> 8, k = i & 255;
        int row = r0 + r;
        xt[r][k] = (row < n) ? X[(size_t)row * 256 + k] : 0.f;
    }
    __syncthreads();
    float acc[G1_ROWS];
#pragma unroll
    for (int r = 0; r < G1_ROWS; ++r) acc[r] = 0.f;
    for (int k = 0; k < 256; ++k) {
        float wk = W[k * 128 + j];
#pragma unroll
        for (int r = 0; r < G1_ROWS; ++r) acc[r] += xt[r][k] * wk;
    }
    float bj = b[j];
    for (int r = 0; r < G1_ROWS; ++r) {
        int row = r0 + r;
        if (row < n) {
            float val = fmaxf(acc[r] + bj, 0.f);
            H[(size_t)row * 128 + j] = val;
            MH[(size_t)row * 128 + j] = __float2half(val * dinv[row]);
        }
    }
}

// -------------------- GEMM2: out = h @ W2 + b2, K=128, cols=64 -------------
#define G2_ROWS 32
__global__ __launch_bounds__(64) void gemm2_kernel(const float* __restrict__ H,
                                                   const float* __restrict__ W,
                                                   const float* __restrict__ b,
                                                   float* __restrict__ O, int n) {
    __shared__ float xt[G2_ROWS][128];
    int j = threadIdx.x;
    int r0 = blockIdx.x * G2_ROWS;
    for (int i = threadIdx.x; i < G2_ROWS * 128; i += 64) {
        int r = i >> 7, k = i & 127;
        int row = r0 + r;
        xt[r][k] = (row < n) ? H[(size_t)row * 128 + k] : 0.f;
    }
    __syncthreads();
    float acc[G2_ROWS];
#pragma unroll
    for (int r = 0; r < G2_ROWS; ++r) acc[r] = 0.f;
    for (int k = 0; k < 128; ++k) {
        float wk = W[k * 64 + j];
#pragma unroll
        for (int r = 0; r < G2_ROWS; ++r) acc[r] += xt[r][k] * wk;
    }
    float bj = b[j];
    for (int r = 0; r < G2_ROWS; ++r) {
        int row = r0 + r;
        if (row < n) O[(size_t)row * 64 + j] = acc[r] + bj;
    }
}

// -------------------- Fused Chebyshev propagation step ---------------------
// One wave per node. Four 16-lane groups (g = lane>>4) each gather a
// different edge's mirror row: lane q = lane&15 loads one float4 (16B = 8
// fp16 features 8q..8q+7). 4-deep unroll -> 16 edges/iteration, 4 in-flight
// 16B loads per lane. Trip count wave-uniform: iters = ceil(m/4) for ALL
// lanes; padding slots (lane >= m) hold dummy row n (zeros, L1-hot).
// Reduce across the 4 groups via shfl_xor(16,32); lanes 0..15 run epilogue.
// acc = sum_e u[col[e]]; agg = -0.5*dinv[v]*acc. Mirror rows hold
// u = dinv[v]*value; MH (may be null) receives the mirror of the value
// written this step. f32 masters stay in h-domain.
// mode 0: tx1 = 0.5x - agg -> TX1 (+MH); OUT = c0*x + c1*tx1
// mode 1: tx2 = x - 2*agg - t0; OUT += ck*tx2; T0 <- tx2 (+MH)
// mode 2: T0 <- relu(OUT + ck*tx2) (+MH)   (layer end)
__global__ __launch_bounds__(256) void prop_kernel(const float* __restrict__ XF,
                                                   const fx4* __restrict__ XH,
                                                   float* __restrict__ T0,
                                                   float* __restrict__ OUT,
                                                   float* __restrict__ TX1,
                                                   fx4* __restrict__ MH,
                                                   const int* __restrict__ rowptr,
                                                   const int* __restrict__ col,
                                                   const float* __restrict__ dinv,
                                                   const float* __restrict__ coeffs,
                                                   int cidx, int mode, int n) {
    int wave = (blockIdx.x * blockDim.x + threadIdx.x) >> 6;
    if (wave >= n) return;
    int lane = threadIdx.x & 63;
    int g = lane >> 4;   // edge group 0..3
    int q = lane & 15;   // feature quad: features 8q..8q+7
    int v = wave;
    int start = rowptr[v];
    int end = rowptr[v + 1];

    fx4 aL0 = {0, 0, 0, 0}, aH0 = {0, 0, 0, 0};
    fx4 aL1 = {0, 0, 0, 0}, aH1 = {0, 0, 0, 0};
    fx4 aL2 = {0, 0, 0, 0}, aH2 = {0, 0, 0, 0};
    fx4 aL3 = {0, 0, 0, 0}, aH3 = {0, 0, 0, 0};

#define CVT_ACC(c, lo, hi)                                        \
    {                                                             \
        float2 p0 = __half22float2(c.h2[0]);                      \
        float2 p1 = __half22float2(c.h2[1]);                      \
        float2 p2 = __half22float2(c.h2[2]);                      \
        float2 p3 = __half22float2(c.h2[3]);                      \
        lo.x += p0.x; lo.y += p0.y; lo.z += p1.x; lo.w += p1.y;   \
        hi.x += p2.x; hi.y += p2.y; hi.z += p3.x; hi.w += p3.y;   \
    }

    for (int e0 = start; e0 < end; e0 += 64) {
        int m = end - e0;
        if (m > 64) m = 64;
        int sE = n;  // dummy zero row for padding slots
        if (lane < m) sE = col[e0 + lane];
        // WAVE-UNIFORM trip count: all lanes run ceil(m/4) iterations.
        int iters = (m + 3) >> 2;
        int t = 0;
        for (; t + 4 <= iters; t += 4) {
            int j0 = 4 * t + g;
            int s0 = __shfl(sE, j0);
            int s1 = __shfl(sE, j0 + 4);
            int s2 = __shfl(sE, j0 + 8);
            int s3 = __shfl(sE, j0 + 12);
            f4h8 c0, c1, c2, c3;
            c0.f4 = XH[(size_t)s0 * 16 + q];
            c1.f4 = XH[(size_t)s1 * 16 + q];
            c2.f4 = XH[(size_t)s2 * 16 + q];
            c3.f4 = XH[(size_t)s3 * 16 + q];
            CVT_ACC(c0, aL0, aH0);
            CVT_ACC(c1, aL1, aH1);
            CVT_ACC(c2, aL2, aH2);
            CVT_ACC(c3, aL3, aH3);
        }
        for (; t < iters; ++t) {
            int j0 = 4 * t + g;
            int s0 = __shfl(sE, j0);
            f4h8 c0;
            c0.f4 = XH[(size_t)s0 * 16 + q];
            CVT_ACC(c0, aL0, aH0);
        }
    }
    fx4 accL = (aL0 + aL1) + (aL2 + aL3);
    fx4 accH = (aH0 + aH1) + (aH2 + aH3);
    // reduce across the 4 edge groups (lanes sharing q)
#define RED(x)                       \
    x += __shfl_xor(x, 16);          \
    x += __shfl_xor(x, 32);
    RED(accL.x) RED(accL.y) RED(accL.z) RED(accL.w)
    RED(accH.x) RED(accH.y) RED(accH.z) RED(accH.w)

    if (lane >= 16) return;  // lanes 0..15 run the epilogue (16 x 2 fx4 = row)

    float dv = dinv[v];
    float sw = -0.5f * dv;
    fx4 g0 = accL * sw;
    fx4 g1 = accH * sw;

    size_t idx0 = (size_t)v * 32 + 2 * q;
    const fx4* __restrict__ X4 = reinterpret_cast<const fx4*>(XF);
    fx4 self0 = X4[idx0];
    fx4 self1 = X4[idx0 + 1];
    fx4 wr0, wr1;

    if (mode == 0) {
        float c0 = coeffs[cidx];
        float c1 = coeffs[cidx + 1];
        wr0 = 0.5f * self0 - g0;
        wr1 = 0.5f * self1 - g1;
        reinterpret_cast<fx4*>(TX1)[idx0] = wr0;
        reinterpret_cast<fx4*>(TX1)[idx0 + 1] = wr1;
        fx4 o0 = c0 * self0 + c1 * wr0;
        fx4 o1 = c0 * self1 + c1 * wr1;
        reinterpret_cast<fx4*>(OUT)[idx0] = o0;
        reinterpret_cast<fx4*>(OUT)[idx0 + 1] = o1;
    } else {
        float ck = coeffs[cidx];
        fx4 t00 = reinterpret_cast<const fx4*>(T0)[idx0];
        fx4 t01 = reinterpret_cast<const fx4*>(T0)[idx0 + 1];
        fx4 t20 = self0 - 2.f * g0 - t00;
        fx4 t21 = self1 - 2.f * g1 - t01;
        fx4 o0 = reinterpret_cast<const fx4*>(OUT)[idx0] + ck * t20;
        fx4 o1 = reinterpret_cast<const fx4*>(OUT)[idx0 + 1] + ck * t21;
        if (mode == 1) {
            wr0 = t20;
            wr1 = t21;
            reinterpret_cast<fx4*>(T0)[idx0] = wr0;
            reinterpret_cast<fx4*>(T0)[idx0 + 1] = wr1;
            reinterpret_cast<fx4*>(OUT)[idx0] = o0;
            reinterpret_cast<fx4*>(OUT)[idx0 + 1] = o1;
        } else {
            wr0.x = fmaxf(o0.x, 0.f); wr0.y = fmaxf(o0.y, 0.f);
            wr0.z = fmaxf(o0.z, 0.f); wr0.w = fmaxf(o0.w, 0.f);
            wr1.x = fmaxf(o1.x, 0.f); wr1.y = fmaxf(o1.y, 0.f);
            wr1.z = fmaxf(o1.z, 0.f); wr1.w = fmaxf(o1.w, 0.f);
            reinterpret_cast<fx4*>(T0)[idx0] = wr0;
            reinterpret_cast<fx4*>(T0)[idx0 + 1] = wr1;
        }
    }
    if (MH) {
        f4h8 u;
        u.h2[0] = __floats2half2_rn(wr0.x * dv, wr0.y * dv);
        u.h2[1] = __floats2half2_rn(wr0.z * dv, wr0.w * dv);
        u.h2[2] = __floats2half2_rn(wr1.x * dv, wr1.y * dv);
        u.h2[3] = __floats2half2_rn(wr1.z * dv, wr1.w * dv);
        MH[(size_t)v * 16 + q] = u.f4;
    }
}

// ---------------------------------------------------------------------------

extern "C" void kernel_launch(void* const* d_in, const int* in_sizes, int n_in,
                              void* d_out, int out_size, void* d_ws, size_t ws_size,
                              hipStream_t stream) {
    const float* x      = (const float*)d_in[0];
    const int*   ei     = (const int*)d_in[1];
    const float* W1     = (const float*)d_in[2];
    const float* b1     = (const float*)d_in[3];
    const float* coeffs = (const float*)d_in[4];
    const float* W2     = (const float*)d_in[5];
    const float* b2     = (const float*)d_in[6];
    float* out = (float*)d_out;

    const int n = in_sizes[0] / 256;
    const int E = in_sizes[1] / 2;
    const int* src = ei;
    const int* dst = ei + E;

    char* ws = (char*)d_ws;
    size_t off = 0;
    auto alloc = [&](size_t bytes) -> void* {
        off = (off + 255) & ~(size_t)255;
        void* p = (void*)(ws + off);
        off += bytes;
        return p;
    };
    size_t bufBytes = (size_t)n * 128 * sizeof(float);
    size_t mirBytes = (size_t)(n + 1) * 128 * sizeof(__half);  // +1 dummy zero row
    float*  bufA   = (float*)alloc(bufBytes);
    float*  bufB   = (float*)alloc(bufBytes);
    float*  bufC   = (float*)alloc(bufBytes);
    __half* mirA   = (__half*)alloc(mirBytes);
    __half* mirB   = (__half*)alloc(mirBytes);
    int*    col    = (int*)alloc((size_t)E * sizeof(int));
    int*    degs   = (int*)alloc((size_t)n * sizeof(int));
    int*    cntd   = (int*)alloc((size_t)n * sizeof(int));
    int*    rowptr = (int*)alloc((size_t)(n + 1) * sizeof(int));
    int*    cursor = (int*)alloc((size_t)n * sizeof(int));
    int*    bsum   = (int*)alloc(1024 * sizeof(int));
    float*  dinv   = (float*)alloc((size_t)n * sizeof(float));

    (void)hipMemsetAsync(degs, 0, (size_t)n * sizeof(int), stream);
    (void)hipMemsetAsync(cntd, 0, (size_t)n * sizeof(int), stream);

    // ---- CSR build (by dst), col-only records ----
    hist_kernel<<<2048, 256, 0, stream>>>(src, dst, degs, cntd, E);
    dinv_kernel<<<(n + 255) / 256, 256, 0, stream>>>(degs, dinv, n);
    int nchunk = (n + SCAN_CHUNK - 1) / SCAN_CHUNK;
    scan_chunk_sum<<<nchunk, SCAN_BLOCK, 0, stream>>>(cntd, bsum, n);
    scan_bsum<<<1, 64, 0, stream>>>(bsum, nchunk);
    scan_write<<<nchunk, SCAN_BLOCK, 0, stream>>>(cntd, bsum, rowptr, cursor, n, E);
    scatter_kernel<<<4096, 256, 0, stream>>>(src, dst, cursor, col, E);

    // ---- h = relu(x @ W1 + b1) + fused pre-scaled fp16 mirror ----
    gemm1_kernel<<<(n + G1_ROWS - 1) / G1_ROWS, 128, 0, stream>>>(x, W1, b1, dinv,
                                                                  bufA, mirA, n);
    pad_kernel<<<1, 256, 0, stream>>>(mirA, mirB, n);

    // ---- 2 BernConv layers ----
    int pgrid = (n + 3) / 4;  // 4 waves (nodes) per 256-thread block
    float*  A  = bufA;
    float*  B  = bufB;
    float*  C  = bufC;
    __half* mA = mirA;
    __half* mB = mirB;
    for (int l = 0; l < 2; ++l) {
        // k=0,1 fused: tx1 = 0.5x - agg(x) -> B (+mirror mB); OUT = c0*x + c1*tx1
        prop_kernel<<<pgrid, 256, 0, stream>>>(A, (const fx4*)mA, A, C, B, (fx4*)mB,
                                               rowptr, col, dinv, coeffs,
                                               l * 11 + 0, 0, n);
        float*  t0 = A;  __half* m0 = mA;
        float*  t1 = B;  __half* m1 = mB;
        for (int k = 2; k <= 9; ++k) {
            // gather from t1's mirror m1; tx2 overwrites t0 (+mirror m0)
            prop_kernel<<<pgrid, 256, 0, stream>>>(t1, (const fx4*)m1, t0, C, nullptr,
                                                   (fx4*)m0, rowptr, col, dinv, coeffs,
                                                   l * 11 + k, 1, n);
            float* tf = t0; t0 = t1; t1 = tf;
            __half* tm = m0; m0 = m1; m1 = tm;
        }
        // k=10: fold last term + ReLU -> t0 (+mirror m0 if another layer follows)
        prop_kernel<<<pgrid, 256, 0, stream>>>(t1, (const fx4*)m1, t0, C, nullptr,
                                               (l == 0) ? (fx4*)m0 : nullptr, rowptr,
                                               col, dinv, coeffs, l * 11 + 10, 2, n);
        A = t0; mA = m0;   // next layer input
        B = t1; mB = m1;
    }

    // ---- out = h @ W2 + b2 ----
    gemm2_kernel<<<(n + G2_ROWS - 1) / G2_ROWS, 64, 0, stream>>>(A, W2, b2, out, n);
}